// Round 1
// baseline (30902.231 us; speedup 1.0000x reference)
//
#include <hip/hip_runtime.h>
#include <hip/hip_bf16.h>
#include <math.h>

// Problem constants
#define S31   31
#define KC    64
#define KS    7
#define KK    49          // 7*7
#define IMG   128
#define HW    16384       // 128*128
#define LAM   0.1f
#define BNEPS 1e-5f

// ---------------------------------------------------------------------------
// Weight reorder: wz_r[lyr][ic][k][oc], wenc_r[lyr][k][oc], wfe_r[k][oc]
// ---------------------------------------------------------------------------
__global__ void reorder_weights(const float* __restrict__ Wz,
                                const float* __restrict__ Wenc,
                                const float* __restrict__ Wfe,
                                float* __restrict__ wz_r,
                                float* __restrict__ wenc_r,
                                float* __restrict__ wfe_r) {
    int tid = blockIdx.x * 256 + threadIdx.x;
    const int NZ = 3 * KC * KK * KC;      // 602112
    const int NE = 3 * KK * KC;           // 9408
    const int NF = KK * KC;               // 3136
    if (tid < NZ) {
        // dest: ((lyr*64+ic)*49 + k)*64 + oc
        int oc = tid & 63;
        int r  = tid >> 6;
        int k  = r % KK;
        int r2 = r / KK;
        int ic = r2 & 63;
        int lyr = r2 >> 6;
        // src: W_z[lyr][oc][ic][k]
        wz_r[tid] = Wz[(((size_t)lyr * KC + oc) * KC + ic) * KK + k];
    } else if (tid < NZ + NE) {
        int t = tid - NZ;
        int oc = t & 63;
        int kk = t >> 6;
        int k  = kk % KK;
        int lyr = kk / KK;
        // src: W_enc[lyr][oc][0][k]
        wenc_r[t] = Wenc[((size_t)lyr * KC + oc) * KK + k];
    } else if (tid < NZ + NE + NF) {
        int t = tid - NZ - NE;
        int oc = t & 63;
        int k  = t >> 6;
        wfe_r[t] = Wfe[oc * KK + k];
    }
}

// ---------------------------------------------------------------------------
// 1 -> 64 channel conv (+optional add of csc) + softshrink.
// Used for: feature extractor (fe) and encoder (enc).
// block: 256 threads = 16x16 pixel tile; grid (64 tiles, 31 bands)
// ---------------------------------------------------------------------------
__global__ __launch_bounds__(256) void conv1to64(
        const float* __restrict__ src,    // [31, HW]
        const float* __restrict__ wr,     // [49*64] layout [k][oc]
        const float* __restrict__ bias,   // [64]
        const float* __restrict__ addsrc, // [31,64,HW] or nullptr
        float* __restrict__ dst)          // [31,64,HW]
{
    int s    = blockIdx.y;
    int tile = blockIdx.x;
    int tx = threadIdx.x & 15, ty = threadIdx.x >> 4;
    int h0 = (tile >> 3) << 4, w0 = (tile & 7) << 4;

    __shared__ float t_s[22 * 22];
    const float* sp = src + (size_t)s * HW;
    for (int i = threadIdx.x; i < 484; i += 256) {
        int r = i / 22, c = i - r * 22;
        int hh = h0 - 3 + r, ww = w0 - 3 + c;
        t_s[i] = (hh >= 0 && hh < IMG && ww >= 0 && ww < IMG) ? sp[hh * IMG + ww] : 0.f;
    }
    __syncthreads();

    float acc[KC];
#pragma unroll
    for (int i = 0; i < KC; i++) acc[i] = 0.f;

#pragma unroll 1
    for (int kh = 0; kh < KS; kh++) {
#pragma unroll
        for (int kw = 0; kw < KS; kw++) {
            float v = t_s[(ty + kh) * 22 + tx + kw];
            const float* wk = wr + (kh * KS + kw) * KC;
#pragma unroll
            for (int oc = 0; oc < KC; oc++) acc[oc] += v * wk[oc];
        }
    }

    int pix = (h0 + ty) * IMG + (w0 + tx);
    size_t base = ((size_t)s * KC) * HW + pix;
#pragma unroll 8
    for (int oc = 0; oc < KC; oc++) {
        float v = acc[oc] + bias[oc];
        if (addsrc) v += addsrc[base + (size_t)oc * HW];
        v = (v > LAM) ? (v - LAM) : ((v < -LAM) ? (v + LAM) : 0.f);
        dst[base + (size_t)oc * HW] = v;
    }
}

// ---------------------------------------------------------------------------
// 64 -> 1 channel conv. mode: if xsub != null, out = xsub - (conv+b) (decoder
// residual); else out = conv+b (last conv).
// ---------------------------------------------------------------------------
__global__ __launch_bounds__(256) void conv64to1(
        const float* __restrict__ src,   // [31,64,HW]
        const float* __restrict__ w,     // [64*49] layout [ic][k]
        const float* __restrict__ bias,  // [1]
        const float* __restrict__ xsub,  // [31,HW] or nullptr
        float* __restrict__ dst)         // [31,HW]
{
    int s    = blockIdx.y;
    int tile = blockIdx.x;
    int tx = threadIdx.x & 15, ty = threadIdx.x >> 4;
    int h0 = (tile >> 3) << 4, w0 = (tile & 7) << 4;

    __shared__ float t_s[22 * 22];
    float acc = 0.f;

    for (int ic = 0; ic < KC; ic++) {
        __syncthreads();
        const float* sp = src + ((size_t)s * KC + ic) * HW;
        for (int i = threadIdx.x; i < 484; i += 256) {
            int r = i / 22, c = i - r * 22;
            int hh = h0 - 3 + r, ww = w0 - 3 + c;
            t_s[i] = (hh >= 0 && hh < IMG && ww >= 0 && ww < IMG) ? sp[hh * IMG + ww] : 0.f;
        }
        __syncthreads();
        const float* wk = w + ic * KK;
#pragma unroll 1
        for (int kh = 0; kh < KS; kh++) {
#pragma unroll
            for (int kw = 0; kw < KS; kw++) {
                acc += t_s[(ty + kh) * 22 + tx + kw] * wk[kh * KS + kw];
            }
        }
    }
    float v = acc + bias[0];
    int pix = (h0 + ty) * IMG + (w0 + tx);
    if (xsub) v = xsub[(size_t)s * HW + pix] - v;
    dst[(size_t)s * HW + pix] = v;
}

// ---------------------------------------------------------------------------
// 64 -> 64 channel conv (the heavy one): zpre = conv(tmp, W_z) + b_z
// Weights reordered [ic][k][oc] -> inner oc loads are wave-uniform (scalar).
// ---------------------------------------------------------------------------
__global__ __launch_bounds__(256) void conv_z(
        const float* __restrict__ src,  // [31,64,HW] (tmp)
        const float* __restrict__ wr,   // [64*49*64] layout [ic][k][oc]
        const float* __restrict__ bias, // [64]
        float* __restrict__ dst)        // [31,64,HW] (zpre)
{
    int s    = blockIdx.y;
    int tile = blockIdx.x;
    int tx = threadIdx.x & 15, ty = threadIdx.x >> 4;
    int h0 = (tile >> 3) << 4, w0 = (tile & 7) << 4;

    __shared__ float t_s[22 * 22];
    float acc[KC];
#pragma unroll
    for (int i = 0; i < KC; i++) acc[i] = 0.f;

    for (int ic = 0; ic < KC; ic++) {
        __syncthreads();
        const float* sp = src + ((size_t)s * KC + ic) * HW;
        for (int i = threadIdx.x; i < 484; i += 256) {
            int r = i / 22, c = i - r * 22;
            int hh = h0 - 3 + r, ww = w0 - 3 + c;
            t_s[i] = (hh >= 0 && hh < IMG && ww >= 0 && ww < IMG) ? sp[hh * IMG + ww] : 0.f;
        }
        __syncthreads();
        const float* wp = wr + ic * KK * KC;
#pragma unroll 1
        for (int kh = 0; kh < KS; kh++) {
#pragma unroll
            for (int kw = 0; kw < KS; kw++) {
                float v = t_s[(ty + kh) * 22 + tx + kw];
                const float* wk = wp + (kh * KS + kw) * KC;
#pragma unroll
                for (int oc = 0; oc < KC; oc++) acc[oc] += v * wk[oc];
            }
        }
    }

    int pix = (h0 + ty) * IMG + (w0 + tx);
    size_t base = ((size_t)s * KC) * HW + pix;
#pragma unroll 8
    for (int oc = 0; oc < KC; oc++) {
        dst[base + (size_t)oc * HW] = acc[oc] + bias[oc];
    }
}

// ---------------------------------------------------------------------------
// BN statistics per (s, c): mean and rsqrt(var+eps) over HW pixels.
// One block per (s,c).
// ---------------------------------------------------------------------------
__global__ __launch_bounds__(256) void bn_reduce(
        const float* __restrict__ zpre,  // [31,64,HW]
        float* __restrict__ stats)       // [31*64][2]
{
    int sc = blockIdx.x;
    const float* p = zpre + (size_t)sc * HW;
    float s1 = 0.f, s2 = 0.f;
    for (int i = threadIdx.x; i < HW; i += 256) {
        float v = p[i];
        s1 += v;
        s2 += v * v;
    }
#pragma unroll
    for (int off = 32; off >= 1; off >>= 1) {
        s1 += __shfl_down(s1, off, 64);
        s2 += __shfl_down(s2, off, 64);
    }
    __shared__ float a1[4], a2[4];
    int wid = threadIdx.x >> 6, lane = threadIdx.x & 63;
    if (lane == 0) { a1[wid] = s1; a2[wid] = s2; }
    __syncthreads();
    if (threadIdx.x == 0) {
        float t1 = a1[0] + a1[1] + a1[2] + a1[3];
        float t2 = a2[0] + a2[1] + a2[2] + a2[3];
        float mu = t1 * (1.f / HW);
        float var = t2 * (1.f / HW) - mu * mu;
        if (var < 0.f) var = 0.f;
        stats[sc * 2]     = mu;
        stats[sc * 2 + 1] = rsqrtf(var + BNEPS);
    }
}

// ---------------------------------------------------------------------------
// Directional gated band scan. Each thread owns one (c,h,w) location and
// walks the 31 bands sequentially (the only sequential dependency).
// z = sigmoid(BN(zpre)*gamma+beta); csc[s] = z*prev + (1-z)*tmp (first band
// in scan order passes through ungated).
// ---------------------------------------------------------------------------
__global__ __launch_bounds__(256) void band_scan(
        const float* __restrict__ tmp,   // [31,64,HW]
        const float* __restrict__ zpre,  // [31,64,HW]
        const float* __restrict__ stats, // [31*64][2]
        const float* __restrict__ gamma, // [64]
        const float* __restrict__ beta,  // [64]
        float* __restrict__ csc,         // [31,64,HW]
        int fwd)
{
    int idx = blockIdx.x * 256 + threadIdx.x;  // 0 .. 64*HW-1
    int c = idx >> 14;
    float g = gamma[c], be = beta[c];
    float prev = 0.f;
    for (int step = 0; step < S31; step++) {
        int s = fwd ? step : (S31 - 1 - step);
        size_t off = (size_t)s * KC * HW + idx;
        float t  = tmp[off];
        float zp = zpre[off];
        float mu = stats[(s * KC + c) * 2];
        float rs = stats[(s * KC + c) * 2 + 1];
        float zn = (zp - mu) * rs * g + be;
        float z  = 1.f / (1.f + expf(-zn));
        float cur = (step == 0) ? t : (z * prev + (1.f - z) * t);
        csc[off] = cur;
        prev = cur;
    }
}

// ---------------------------------------------------------------------------
extern "C" void kernel_launch(void* const* d_in, const int* in_sizes, int n_in,
                              void* d_out, int out_size, void* d_ws, size_t ws_size,
                              hipStream_t stream) {
    const float* x      = (const float*)d_in[0];   // [1,31,128,128]
    const float* W_fe   = (const float*)d_in[1];   // [64,1,7,7]
    const float* b_fe   = (const float*)d_in[2];   // [64]
    const float* W_enc  = (const float*)d_in[3];   // [3,64,1,7,7]
    const float* b_enc  = (const float*)d_in[4];   // [3,64]
    const float* W_dec  = (const float*)d_in[5];   // [3,1,64,7,7]
    const float* b_dec  = (const float*)d_in[6];   // [3,1]
    const float* W_last = (const float*)d_in[7];   // [1,64,7,7]
    const float* b_last = (const float*)d_in[8];   // [1]
    const float* W_z    = (const float*)d_in[9];   // [3,64,64,7,7]
    const float* b_z    = (const float*)d_in[10];  // [3,64]
    const float* bn_g   = (const float*)d_in[11];  // [3,64]
    const float* bn_b   = (const float*)d_in[12];  // [3,64]

    float* out     = (float*)d_out;
    float* csc     = out;                               // [31,1,64,128,128]
    float* outputs = out + (size_t)S31 * KC * HW;       // [1,31,128,128]

    char* ws = (char*)d_ws;
    float* tmp    = (float*)ws; ws += (size_t)S31 * KC * HW * 4;
    float* zpre   = (float*)ws; ws += (size_t)S31 * KC * HW * 4;
    float* res    = (float*)ws; ws += (size_t)S31 * HW * 4;
    float* stats  = (float*)ws; ws += (size_t)S31 * KC * 2 * 4;
    float* wz_r   = (float*)ws; ws += (size_t)3 * KC * KK * KC * 4;
    float* wenc_r = (float*)ws; ws += (size_t)3 * KK * KC * 4;
    float* wfe_r  = (float*)ws; ws += (size_t)KK * KC * 4;

    // 1) weight reorder
    {
        int total = 3 * KC * KK * KC + 3 * KK * KC + KK * KC;
        reorder_weights<<<(total + 255) / 256, 256, 0, stream>>>(
            W_z, W_enc, W_fe, wz_r, wenc_r, wfe_r);
    }

    dim3 gconv(64, S31);

    // 2) csc = softshrink(conv_fe(x))
    conv1to64<<<gconv, 256, 0, stream>>>(x, wfe_r, b_fe, nullptr, csc);

    for (int it = 0; it < 3; it++) {
        int lyr = it;  // it % ITERS with ITERS == 3
        // res = x - (conv_dec(csc) + b_dec)
        conv64to1<<<gconv, 256, 0, stream>>>(
            csc, W_dec + (size_t)lyr * KC * KK, b_dec + lyr, x, res);
        // tmp = softshrink(csc + conv_enc(res) + b_enc)
        conv1to64<<<gconv, 256, 0, stream>>>(
            res, wenc_r + (size_t)lyr * KK * KC, b_enc + (size_t)lyr * KC, csc, tmp);
        // zpre = conv_z(tmp) + b_z
        conv_z<<<gconv, 256, 0, stream>>>(
            tmp, wz_r + (size_t)lyr * KC * KK * KC, b_z + (size_t)lyr * KC, zpre);
        // BN stats
        bn_reduce<<<S31 * KC, 256, 0, stream>>>(zpre, stats);
        // gated directional scan -> csc
        band_scan<<<(KC * HW) / 256, 256, 0, stream>>>(
            tmp, zpre, stats, bn_g + (size_t)lyr * KC, bn_b + (size_t)lyr * KC,
            csc, (it % 2 == 0) ? 1 : 0);
    }

    // 3) outputs = conv_last(csc) + b_last
    conv64to1<<<gconv, 256, 0, stream>>>(csc, W_last, b_last, nullptr, outputs);
}

// Round 2
// 10707.524 us; speedup vs baseline: 2.8860x; 2.8860x over previous
//
#include <hip/hip_runtime.h>
#include <hip/hip_bf16.h>
#include <math.h>

// Problem constants
#define S31   31
#define KC    64
#define KS    7
#define KK    49          // 7*7
#define IMG   128
#define HW    16384       // 128*128
#define LAM   0.1f
#define BNEPS 1e-5f

// ---------------------------------------------------------------------------
// Weight reorder: wz_r[lyr][ic][k][oc], wenc_r[lyr][k][oc], wfe_r[k][oc]
// ---------------------------------------------------------------------------
__global__ void reorder_weights(const float* __restrict__ Wz,
                                const float* __restrict__ Wenc,
                                const float* __restrict__ Wfe,
                                float* __restrict__ wz_r,
                                float* __restrict__ wenc_r,
                                float* __restrict__ wfe_r) {
    int tid = blockIdx.x * 256 + threadIdx.x;
    const int NZ = 3 * KC * KK * KC;      // 602112
    const int NE = 3 * KK * KC;           // 9408
    const int NF = KK * KC;               // 3136
    if (tid < NZ) {
        // dest: ((lyr*64+ic)*49 + k)*64 + oc
        int oc = tid & 63;
        int r  = tid >> 6;
        int k  = r % KK;
        int r2 = r / KK;
        int ic = r2 & 63;
        int lyr = r2 >> 6;
        // src: W_z[lyr][oc][ic][k]
        wz_r[tid] = Wz[(((size_t)lyr * KC + oc) * KC + ic) * KK + k];
    } else if (tid < NZ + NE) {
        int t = tid - NZ;
        int oc = t & 63;
        int kk = t >> 6;
        int k  = kk % KK;
        int lyr = kk / KK;
        // src: W_enc[lyr][oc][0][k]
        wenc_r[t] = Wenc[((size_t)lyr * KC + oc) * KK + k];
    } else if (tid < NZ + NE + NF) {
        int t = tid - NZ - NE;
        int oc = t & 63;
        int k  = t >> 6;
        wfe_r[t] = Wfe[oc * KK + k];
    }
}

// ---------------------------------------------------------------------------
// 1 -> 64 channel conv (+optional add of csc) + softshrink.
// block: 256 threads = 16x16 pixel tile; grid (64 tiles, 31 bands)
// NOTE: all loops touching acc[] are FULLY unrolled (constant indices) so
// SROA keeps acc in VGPRs — partial unroll demotes the array to scratch
// (round-1 bug: 52 GB scratch writes, VGPR_Count=44).
// ---------------------------------------------------------------------------
__global__ __launch_bounds__(256) void conv1to64(
        const float* __restrict__ src,    // [31, HW]
        const float* __restrict__ wr,     // [49*64] layout [k][oc]
        const float* __restrict__ bias,   // [64]
        const float* __restrict__ addsrc, // [31,64,HW] or nullptr
        float* __restrict__ dst)          // [31,64,HW]
{
    int s    = blockIdx.y;
    int tile = blockIdx.x;
    int tx = threadIdx.x & 15, ty = threadIdx.x >> 4;
    int h0 = (tile >> 3) << 4, w0 = (tile & 7) << 4;

    __shared__ float t_s[22 * 22];
    const float* sp = src + (size_t)s * HW;
    for (int i = threadIdx.x; i < 484; i += 256) {
        int r = i / 22, c = i - r * 22;
        int hh = h0 - 3 + r, ww = w0 - 3 + c;
        t_s[i] = (hh >= 0 && hh < IMG && ww >= 0 && ww < IMG) ? sp[hh * IMG + ww] : 0.f;
    }
    __syncthreads();

    float acc[KC];
#pragma unroll
    for (int i = 0; i < KC; i++) acc[i] = 0.f;

#pragma unroll 1
    for (int kh = 0; kh < KS; kh++) {
#pragma unroll
        for (int kw = 0; kw < KS; kw++) {
            float v = t_s[(ty + kh) * 22 + tx + kw];
            const float* wk = wr + (kh * KS + kw) * KC;
#pragma unroll
            for (int oc = 0; oc < KC; oc++) acc[oc] += v * wk[oc];
        }
    }

    int pix = (h0 + ty) * IMG + (w0 + tx);
    size_t base = ((size_t)s * KC) * HW + pix;
#pragma unroll
    for (int oc = 0; oc < KC; oc++) {
        float v = acc[oc] + bias[oc];
        if (addsrc) v += addsrc[base + (size_t)oc * HW];
        v = (v > LAM) ? (v - LAM) : ((v < -LAM) ? (v + LAM) : 0.f);
        dst[base + (size_t)oc * HW] = v;
    }
}

// ---------------------------------------------------------------------------
// 64 -> 1 channel conv. If xsub != null, out = xsub - (conv+b); else conv+b.
// ---------------------------------------------------------------------------
__global__ __launch_bounds__(256) void conv64to1(
        const float* __restrict__ src,   // [31,64,HW]
        const float* __restrict__ w,     // [64*49] layout [ic][k]
        const float* __restrict__ bias,  // [1]
        const float* __restrict__ xsub,  // [31,HW] or nullptr
        float* __restrict__ dst)         // [31,HW]
{
    int s    = blockIdx.y;
    int tile = blockIdx.x;
    int tx = threadIdx.x & 15, ty = threadIdx.x >> 4;
    int h0 = (tile >> 3) << 4, w0 = (tile & 7) << 4;

    __shared__ float t_s[22 * 22];
    float acc = 0.f;

    for (int ic = 0; ic < KC; ic++) {
        __syncthreads();
        const float* sp = src + ((size_t)s * KC + ic) * HW;
        for (int i = threadIdx.x; i < 484; i += 256) {
            int r = i / 22, c = i - r * 22;
            int hh = h0 - 3 + r, ww = w0 - 3 + c;
            t_s[i] = (hh >= 0 && hh < IMG && ww >= 0 && ww < IMG) ? sp[hh * IMG + ww] : 0.f;
        }
        __syncthreads();
        const float* wk = w + ic * KK;
#pragma unroll 1
        for (int kh = 0; kh < KS; kh++) {
#pragma unroll
            for (int kw = 0; kw < KS; kw++) {
                acc += t_s[(ty + kh) * 22 + tx + kw] * wk[kh * KS + kw];
            }
        }
    }
    float v = acc + bias[0];
    int pix = (h0 + ty) * IMG + (w0 + tx);
    if (xsub) v = xsub[(size_t)s * HW + pix] - v;
    dst[(size_t)s * HW + pix] = v;
}

// ---------------------------------------------------------------------------
// 64 -> 64 channel conv (the heavy one): zpre = conv(tmp, W_z) + b_z
// Weights reordered [ic][k][oc]; inner oc reads are wave-uniform -> scalar
// loads (s_load), FMAs keep the 64 accumulators in VGPRs (full unroll).
// ---------------------------------------------------------------------------
__global__ __launch_bounds__(256) void conv_z(
        const float* __restrict__ src,  // [31,64,HW] (tmp)
        const float* __restrict__ wr,   // [64*49*64] layout [ic][k][oc]
        const float* __restrict__ bias, // [64]
        float* __restrict__ dst)        // [31,64,HW] (zpre)
{
    int s    = blockIdx.y;
    int tile = blockIdx.x;
    int tx = threadIdx.x & 15, ty = threadIdx.x >> 4;
    int h0 = (tile >> 3) << 4, w0 = (tile & 7) << 4;

    __shared__ float t_s[22 * 22];
    float acc[KC];
#pragma unroll
    for (int i = 0; i < KC; i++) acc[i] = 0.f;

    for (int ic = 0; ic < KC; ic++) {
        __syncthreads();
        const float* sp = src + ((size_t)s * KC + ic) * HW;
        for (int i = threadIdx.x; i < 484; i += 256) {
            int r = i / 22, c = i - r * 22;
            int hh = h0 - 3 + r, ww = w0 - 3 + c;
            t_s[i] = (hh >= 0 && hh < IMG && ww >= 0 && ww < IMG) ? sp[hh * IMG + ww] : 0.f;
        }
        __syncthreads();
        const float* wp = wr + ic * KK * KC;
#pragma unroll 1
        for (int kh = 0; kh < KS; kh++) {
#pragma unroll
            for (int kw = 0; kw < KS; kw++) {
                float v = t_s[(ty + kh) * 22 + tx + kw];
                const float* wk = wp + (kh * KS + kw) * KC;
#pragma unroll
                for (int oc = 0; oc < KC; oc++) acc[oc] += v * wk[oc];
            }
        }
    }

    int pix = (h0 + ty) * IMG + (w0 + tx);
    size_t base = ((size_t)s * KC) * HW + pix;
#pragma unroll
    for (int oc = 0; oc < KC; oc++) {
        dst[base + (size_t)oc * HW] = acc[oc] + bias[oc];
    }
}

// ---------------------------------------------------------------------------
// BN statistics per (s, c): mean and rsqrt(var+eps) over HW pixels.
// ---------------------------------------------------------------------------
__global__ __launch_bounds__(256) void bn_reduce(
        const float* __restrict__ zpre,  // [31,64,HW]
        float* __restrict__ stats)       // [31*64][2]
{
    int sc = blockIdx.x;
    const float* p = zpre + (size_t)sc * HW;
    float s1 = 0.f, s2 = 0.f;
    for (int i = threadIdx.x; i < HW; i += 256) {
        float v = p[i];
        s1 += v;
        s2 += v * v;
    }
#pragma unroll
    for (int off = 32; off >= 1; off >>= 1) {
        s1 += __shfl_down(s1, off, 64);
        s2 += __shfl_down(s2, off, 64);
    }
    __shared__ float a1[4], a2[4];
    int wid = threadIdx.x >> 6, lane = threadIdx.x & 63;
    if (lane == 0) { a1[wid] = s1; a2[wid] = s2; }
    __syncthreads();
    if (threadIdx.x == 0) {
        float t1 = a1[0] + a1[1] + a1[2] + a1[3];
        float t2 = a2[0] + a2[1] + a2[2] + a2[3];
        float mu = t1 * (1.f / HW);
        float var = t2 * (1.f / HW) - mu * mu;
        if (var < 0.f) var = 0.f;
        stats[sc * 2]     = mu;
        stats[sc * 2 + 1] = rsqrtf(var + BNEPS);
    }
}

// ---------------------------------------------------------------------------
// Directional gated band scan: each thread owns one (c,h,w) and walks the
// 31 bands sequentially.
// ---------------------------------------------------------------------------
__global__ __launch_bounds__(256) void band_scan(
        const float* __restrict__ tmp,   // [31,64,HW]
        const float* __restrict__ zpre,  // [31,64,HW]
        const float* __restrict__ stats, // [31*64][2]
        const float* __restrict__ gamma, // [64]
        const float* __restrict__ beta,  // [64]
        float* __restrict__ csc,         // [31,64,HW]
        int fwd)
{
    int idx = blockIdx.x * 256 + threadIdx.x;  // 0 .. 64*HW-1
    int c = idx >> 14;
    float g = gamma[c], be = beta[c];
    float prev = 0.f;
    for (int step = 0; step < S31; step++) {
        int s = fwd ? step : (S31 - 1 - step);
        size_t off = (size_t)s * KC * HW + idx;
        float t  = tmp[off];
        float zp = zpre[off];
        float mu = stats[(s * KC + c) * 2];
        float rs = stats[(s * KC + c) * 2 + 1];
        float zn = (zp - mu) * rs * g + be;
        float z  = 1.f / (1.f + expf(-zn));
        float cur = (step == 0) ? t : (z * prev + (1.f - z) * t);
        csc[off] = cur;
        prev = cur;
    }
}

// ---------------------------------------------------------------------------
extern "C" void kernel_launch(void* const* d_in, const int* in_sizes, int n_in,
                              void* d_out, int out_size, void* d_ws, size_t ws_size,
                              hipStream_t stream) {
    const float* x      = (const float*)d_in[0];   // [1,31,128,128]
    const float* W_fe   = (const float*)d_in[1];   // [64,1,7,7]
    const float* b_fe   = (const float*)d_in[2];   // [64]
    const float* W_enc  = (const float*)d_in[3];   // [3,64,1,7,7]
    const float* b_enc  = (const float*)d_in[4];   // [3,64]
    const float* W_dec  = (const float*)d_in[5];   // [3,1,64,7,7]
    const float* b_dec  = (const float*)d_in[6];   // [3,1]
    const float* W_last = (const float*)d_in[7];   // [1,64,7,7]
    const float* b_last = (const float*)d_in[8];   // [1]
    const float* W_z    = (const float*)d_in[9];   // [3,64,64,7,7]
    const float* b_z    = (const float*)d_in[10];  // [3,64]
    const float* bn_g   = (const float*)d_in[11];  // [3,64]
    const float* bn_b   = (const float*)d_in[12];  // [3,64]

    float* out     = (float*)d_out;
    float* csc     = out;                               // [31,1,64,128,128]
    float* outputs = out + (size_t)S31 * KC * HW;       // [1,31,128,128]

    char* ws = (char*)d_ws;
    float* tmp    = (float*)ws; ws += (size_t)S31 * KC * HW * 4;
    float* zpre   = (float*)ws; ws += (size_t)S31 * KC * HW * 4;
    float* res    = (float*)ws; ws += (size_t)S31 * HW * 4;
    float* stats  = (float*)ws; ws += (size_t)S31 * KC * 2 * 4;
    float* wz_r   = (float*)ws; ws += (size_t)3 * KC * KK * KC * 4;
    float* wenc_r = (float*)ws; ws += (size_t)3 * KK * KC * 4;
    float* wfe_r  = (float*)ws; ws += (size_t)KK * KC * 4;

    // 1) weight reorder
    {
        int total = 3 * KC * KK * KC + 3 * KK * KC + KK * KC;
        reorder_weights<<<(total + 255) / 256, 256, 0, stream>>>(
            W_z, W_enc, W_fe, wz_r, wenc_r, wfe_r);
    }

    dim3 gconv(64, S31);

    // 2) csc = softshrink(conv_fe(x))
    conv1to64<<<gconv, 256, 0, stream>>>(x, wfe_r, b_fe, nullptr, csc);

    for (int it = 0; it < 3; it++) {
        int lyr = it;  // it % ITERS with ITERS == 3
        // res = x - (conv_dec(csc) + b_dec)
        conv64to1<<<gconv, 256, 0, stream>>>(
            csc, W_dec + (size_t)lyr * KC * KK, b_dec + lyr, x, res);
        // tmp = softshrink(csc + conv_enc(res) + b_enc)
        conv1to64<<<gconv, 256, 0, stream>>>(
            res, wenc_r + (size_t)lyr * KK * KC, b_enc + (size_t)lyr * KC, csc, tmp);
        // zpre = conv_z(tmp) + b_z
        conv_z<<<gconv, 256, 0, stream>>>(
            tmp, wz_r + (size_t)lyr * KC * KK * KC, b_z + (size_t)lyr * KC, zpre);
        // BN stats
        bn_reduce<<<S31 * KC, 256, 0, stream>>>(zpre, stats);
        // gated directional scan -> csc
        band_scan<<<(KC * HW) / 256, 256, 0, stream>>>(
            tmp, zpre, stats, bn_g + (size_t)lyr * KC, bn_b + (size_t)lyr * KC,
            csc, (it % 2 == 0) ? 1 : 0);
    }

    // 3) outputs = conv_last(csc) + b_last
    conv64to1<<<gconv, 256, 0, stream>>>(csc, W_last, b_last, nullptr, outputs);
}

// Round 3
// 3298.774 us; speedup vs baseline: 9.3678x; 3.2459x over previous
//
#include <hip/hip_runtime.h>
#include <hip/hip_bf16.h>
#include <math.h>

// Problem constants
#define S31   31
#define KC    64
#define KS    7
#define KK    49          // 7*7
#define IMG   128
#define HW    16384       // 128*128
#define LAM   0.1f
#define BNEPS 1e-5f

#define ASTRIDE 72        // bf16 elems per spatial row in LDS A tile (64 + 8 pad)

typedef __attribute__((ext_vector_type(8))) short  frag8;   // 8 bf16 (4 VGPRs)
typedef __attribute__((ext_vector_type(4))) float  facc4;   // 4 fp32 acc

// fp32 -> bf16 bits, RNE
static __device__ __forceinline__ short f2bf(float f) {
    union { float f; unsigned u; } x; x.f = f;
    unsigned r = x.u + 0x7fffu + ((x.u >> 16) & 1u);
    return (short)(r >> 16);
}

// ---------------------------------------------------------------------------
// Weight reorder:
//  wz_frag[lyr][khkw][ks][og][lane][j] (bf16) — exact MFMA B-fragment order
//    for 16x16x32: k(=ic) = ks*32 + (lane>>4)*8 + j, n(=oc) = og*16 + (lane&15)
//  wenc_r[lyr][k][oc], wfe_r[k][oc] (fp32)
// ---------------------------------------------------------------------------
__global__ void reorder_weights(const float* __restrict__ Wz,
                                const float* __restrict__ Wenc,
                                const float* __restrict__ Wfe,
                                short* __restrict__ wz_frag,
                                float* __restrict__ wenc_r,
                                float* __restrict__ wfe_r) {
    int tid = blockIdx.x * 256 + threadIdx.x;
    const int NZ = 3 * KK * 4096;         // 602112 frag elements
    const int NE = 3 * KK * KC;           // 9408
    const int NF = KK * KC;               // 3136
    if (tid < NZ) {
        int j    = tid & 7;
        int lane = (tid >> 3) & 63;
        int og   = (tid >> 9) & 3;
        int ks   = (tid >> 11) & 1;
        int rem  = tid >> 12;            // lyr*49 + khkw
        int khkw = rem % KK;
        int lyr  = rem / KK;
        int ic = ks * 32 + ((lane >> 4) << 3) + j;
        int oc = (og << 4) + (lane & 15);
        float w = Wz[(((size_t)lyr * KC + oc) * KC + ic) * KK + khkw];
        wz_frag[tid] = f2bf(w);
    } else if (tid < NZ + NE) {
        int t = tid - NZ;
        int oc = t & 63;
        int kk = t >> 6;
        int k  = kk % KK;
        int lyr = kk / KK;
        wenc_r[t] = Wenc[((size_t)lyr * KC + oc) * KK + k];
    } else if (tid < NZ + NE + NF) {
        int t = tid - NZ - NE;
        int oc = t & 63;
        int k  = t >> 6;
        wfe_r[t] = Wfe[oc * KK + k];
    }
}

// ---------------------------------------------------------------------------
// 1 -> 64 channel conv (+optional add) + softshrink.
// 512 threads: 16x16 pixel tile, oc split in two halves of 32 -> 32 fp32
// accumulators per thread stay in arch VGPRs (64 would spill to AGPR shuttle).
// ---------------------------------------------------------------------------
__global__ __launch_bounds__(512) void conv1to64(
        const float* __restrict__ src,    // [31, HW]
        const float* __restrict__ wr,     // [49*64] layout [k][oc]
        const float* __restrict__ bias,   // [64]
        const float* __restrict__ addsrc, // [31,64,HW] or nullptr
        float* __restrict__ dst)          // [31,64,HW]
{
    int s    = blockIdx.y;
    int tile = blockIdx.x;
    int half = threadIdx.x >> 8;          // 0/1 -> oc 0..31 / 32..63
    int t    = threadIdx.x & 255;
    int tx = t & 15, ty = t >> 4;
    int h0 = (tile >> 3) << 4, w0 = (tile & 7) << 4;

    __shared__ float t_s[22 * 22];
    const float* sp = src + (size_t)s * HW;
    for (int i = threadIdx.x; i < 484; i += 512) {
        int r = i / 22, c = i - r * 22;
        int hh = h0 - 3 + r, ww = w0 - 3 + c;
        t_s[i] = (hh >= 0 && hh < IMG && ww >= 0 && ww < IMG) ? sp[hh * IMG + ww] : 0.f;
    }
    __syncthreads();

    float acc[32];
#pragma unroll
    for (int i = 0; i < 32; i++) acc[i] = 0.f;

    const float* wrh = wr + half * 32;
#pragma unroll 1
    for (int kh = 0; kh < KS; kh++) {
#pragma unroll
        for (int kw = 0; kw < KS; kw++) {
            float v = t_s[(ty + kh) * 22 + tx + kw];
            const float* wk = wrh + (kh * KS + kw) * KC;
#pragma unroll
            for (int i = 0; i < 32; i++) acc[i] += v * wk[i];
        }
    }

    int pix = (h0 + ty) * IMG + (w0 + tx);
    size_t base = ((size_t)s * KC + half * 32) * HW + pix;
#pragma unroll
    for (int i = 0; i < 32; i++) {
        float v = acc[i] + bias[half * 32 + i];
        if (addsrc) v += addsrc[base + (size_t)i * HW];
        v = (v > LAM) ? (v - LAM) : ((v < -LAM) ? (v + LAM) : 0.f);
        dst[base + (size_t)i * HW] = v;
    }
}

// ---------------------------------------------------------------------------
// 64 -> 1 channel conv. If xsub != null, out = xsub - (conv+b); else conv+b.
// ---------------------------------------------------------------------------
__global__ __launch_bounds__(256) void conv64to1(
        const float* __restrict__ src,   // [31,64,HW]
        const float* __restrict__ w,     // [64*49] layout [ic][k]
        const float* __restrict__ bias,  // [1]
        const float* __restrict__ xsub,  // [31,HW] or nullptr
        float* __restrict__ dst)         // [31,HW]
{
    int s    = blockIdx.y;
    int tile = blockIdx.x;
    int tx = threadIdx.x & 15, ty = threadIdx.x >> 4;
    int h0 = (tile >> 3) << 4, w0 = (tile & 7) << 4;

    __shared__ float t_s[22 * 22];
    float acc = 0.f;

    for (int ic = 0; ic < KC; ic++) {
        __syncthreads();
        const float* sp = src + ((size_t)s * KC + ic) * HW;
        for (int i = threadIdx.x; i < 484; i += 256) {
            int r = i / 22, c = i - r * 22;
            int hh = h0 - 3 + r, ww = w0 - 3 + c;
            t_s[i] = (hh >= 0 && hh < IMG && ww >= 0 && ww < IMG) ? sp[hh * IMG + ww] : 0.f;
        }
        __syncthreads();
        const float* wk = w + ic * KK;
#pragma unroll 1
        for (int kh = 0; kh < KS; kh++) {
#pragma unroll
            for (int kw = 0; kw < KS; kw++) {
                acc += t_s[(ty + kh) * 22 + tx + kw] * wk[kh * KS + kw];
            }
        }
    }
    float v = acc + bias[0];
    int pix = (h0 + ty) * IMG + (w0 + tx);
    if (xsub) v = xsub[(size_t)s * HW + pix] - v;
    dst[(size_t)s * HW + pix] = v;
}

// ---------------------------------------------------------------------------
// conv_z as bf16 MFMA shift-GEMM: zpre[s][oc][px] = sum_{ic,kh,kw} ...
// Block: 256 thr (4 waves) = 16x16 pixel tile x 64 oc, all 49 taps, K=64 ic.
// A tile: LDS [484 spatial][72 (64 ic + pad)] bf16 (69.7 KB)
// B tap:  LDS 8 KB in exact fragment order, reg-prefetched per tap.
// Per wave per tap: 8 A-frag + 8 B-frag ds_read_b128, 32 MFMAs (16x16x32).
// ---------------------------------------------------------------------------
__global__ __launch_bounds__(256) void conv_z_mfma(
        const float* __restrict__ src,   // [31,64,HW] fp32 (tmp)
        const short* __restrict__ wfrag, // per-layer B-frag buffer (bf16 bits)
        const float* __restrict__ bias,  // [64]
        float* __restrict__ dst)         // [31,64,HW] (zpre)
{
    __shared__ __align__(16) short a_s[484 * ASTRIDE]; // 69,696 B
    __shared__ __align__(16) short b_s[4096];          // 8,192 B

    int s    = blockIdx.y;
    int tile = blockIdx.x;
    int h0 = (tile >> 3) << 4, w0 = (tile & 7) << 4;
    int tid  = threadIdx.x;
    int wave = tid >> 6, lane = tid & 63;
    int q = lane >> 4, m = lane & 15;

    // prefetch B for tap 0 (overlaps A staging)
    const uint4* bsrc = (const uint4*)wfrag;
    uint4 cur0 = bsrc[tid * 2];
    uint4 cur1 = bsrc[tid * 2 + 1];

    // ---- stage A: fp32 [ic][h][w] -> bf16 LDS [sp][ic] (transpose+convert)
    const float* sp_base = src + (size_t)s * KC * HW;
#pragma unroll 1
    for (int ic = 0; ic < KC; ic++) {
        const float* icp = sp_base + (size_t)ic * HW;
#pragma unroll
        for (int rep = 0; rep < 2; rep++) {
            int j = tid + rep * 256;
            if (j < 484) {
                int r = j / 22, c = j - r * 22;
                int hh = h0 - 3 + r, ww = w0 - 3 + c;
                float v = (hh >= 0 && hh < IMG && ww >= 0 && ww < IMG)
                          ? icp[hh * IMG + ww] : 0.f;
                a_s[j * ASTRIDE + ic] = f2bf(v);
            }
        }
    }

    facc4 acc[4][4];
#pragma unroll
    for (int i = 0; i < 4; i++)
#pragma unroll
        for (int j = 0; j < 4; j++)
            acc[i][j] = (facc4){0.f, 0.f, 0.f, 0.f};

    int kh = 0, kw = 0;
#pragma unroll 1
    for (int khkw = 0; khkw < KK; khkw++) {
        // publish this tap's B frags
        ((uint4*)b_s)[tid * 2]     = cur0;
        ((uint4*)b_s)[tid * 2 + 1] = cur1;
        __syncthreads();   // b_s ready; (iter 0: a_s ready too)
        // prefetch next tap
        if (khkw < KK - 1) {
            cur0 = bsrc[(khkw + 1) * 512 + tid * 2];
            cur1 = bsrc[(khkw + 1) * 512 + tid * 2 + 1];
        }

        int sbase = (wave * 4 + kh) * 22 + m + kw;  // A row for pg=0
#pragma unroll
        for (int ks = 0; ks < 2; ks++) {
            frag8 a0 = *(const frag8*)(a_s + (sbase +  0) * ASTRIDE + ks * 32 + q * 8);
            frag8 a1 = *(const frag8*)(a_s + (sbase + 22) * ASTRIDE + ks * 32 + q * 8);
            frag8 a2 = *(const frag8*)(a_s + (sbase + 44) * ASTRIDE + ks * 32 + q * 8);
            frag8 a3 = *(const frag8*)(a_s + (sbase + 66) * ASTRIDE + ks * 32 + q * 8);
            frag8 b0 = *(const frag8*)(b_s + (ks * 4 + 0) * 512 + lane * 8);
            frag8 b1 = *(const frag8*)(b_s + (ks * 4 + 1) * 512 + lane * 8);
            frag8 b2 = *(const frag8*)(b_s + (ks * 4 + 2) * 512 + lane * 8);
            frag8 b3 = *(const frag8*)(b_s + (ks * 4 + 3) * 512 + lane * 8);
            acc[0][0] = __builtin_amdgcn_mfma_f32_16x16x32_bf16(a0, b0, acc[0][0], 0, 0, 0);
            acc[0][1] = __builtin_amdgcn_mfma_f32_16x16x32_bf16(a0, b1, acc[0][1], 0, 0, 0);
            acc[0][2] = __builtin_amdgcn_mfma_f32_16x16x32_bf16(a0, b2, acc[0][2], 0, 0, 0);
            acc[0][3] = __builtin_amdgcn_mfma_f32_16x16x32_bf16(a0, b3, acc[0][3], 0, 0, 0);
            acc[1][0] = __builtin_amdgcn_mfma_f32_16x16x32_bf16(a1, b0, acc[1][0], 0, 0, 0);
            acc[1][1] = __builtin_amdgcn_mfma_f32_16x16x32_bf16(a1, b1, acc[1][1], 0, 0, 0);
            acc[1][2] = __builtin_amdgcn_mfma_f32_16x16x32_bf16(a1, b2, acc[1][2], 0, 0, 0);
            acc[1][3] = __builtin_amdgcn_mfma_f32_16x16x32_bf16(a1, b3, acc[1][3], 0, 0, 0);
            acc[2][0] = __builtin_amdgcn_mfma_f32_16x16x32_bf16(a2, b0, acc[2][0], 0, 0, 0);
            acc[2][1] = __builtin_amdgcn_mfma_f32_16x16x32_bf16(a2, b1, acc[2][1], 0, 0, 0);
            acc[2][2] = __builtin_amdgcn_mfma_f32_16x16x32_bf16(a2, b2, acc[2][2], 0, 0, 0);
            acc[2][3] = __builtin_amdgcn_mfma_f32_16x16x32_bf16(a2, b3, acc[2][3], 0, 0, 0);
            acc[3][0] = __builtin_amdgcn_mfma_f32_16x16x32_bf16(a3, b0, acc[3][0], 0, 0, 0);
            acc[3][1] = __builtin_amdgcn_mfma_f32_16x16x32_bf16(a3, b1, acc[3][1], 0, 0, 0);
            acc[3][2] = __builtin_amdgcn_mfma_f32_16x16x32_bf16(a3, b2, acc[3][2], 0, 0, 0);
            acc[3][3] = __builtin_amdgcn_mfma_f32_16x16x32_bf16(a3, b3, acc[3][3], 0, 0, 0);
        }
        __syncthreads();   // everyone done with b_s before next publish
        kw++; if (kw == KS) { kw = 0; kh++; }
    }

    // ---- epilogue: D layout col(oc-part)=lane&15, row(px col)=q*4+reg
    int prow = h0 + wave * 4;
#pragma unroll
    for (int pg = 0; pg < 4; pg++) {
#pragma unroll
        for (int og = 0; og < 4; og++) {
            int oc = og * 16 + m;
            float bb = bias[oc];
            float* dp = dst + ((size_t)s * KC + oc) * HW
                            + (size_t)(prow + pg) * IMG + w0 + q * 4;
#pragma unroll
            for (int r = 0; r < 4; r++) dp[r] = acc[pg][og][r] + bb;
        }
    }
}

// ---------------------------------------------------------------------------
// BN statistics per (s, c): mean and rsqrt(var+eps) over HW pixels.
// ---------------------------------------------------------------------------
__global__ __launch_bounds__(256) void bn_reduce(
        const float* __restrict__ zpre,  // [31,64,HW]
        float* __restrict__ stats)       // [31*64][2]
{
    int sc = blockIdx.x;
    const float* p = zpre + (size_t)sc * HW;
    float s1 = 0.f, s2 = 0.f;
    for (int i = threadIdx.x; i < HW; i += 256) {
        float v = p[i];
        s1 += v;
        s2 += v * v;
    }
#pragma unroll
    for (int off = 32; off >= 1; off >>= 1) {
        s1 += __shfl_down(s1, off, 64);
        s2 += __shfl_down(s2, off, 64);
    }
    __shared__ float a1[4], a2[4];
    int wid = threadIdx.x >> 6, lane = threadIdx.x & 63;
    if (lane == 0) { a1[wid] = s1; a2[wid] = s2; }
    __syncthreads();
    if (threadIdx.x == 0) {
        float t1 = a1[0] + a1[1] + a1[2] + a1[3];
        float t2 = a2[0] + a2[1] + a2[2] + a2[3];
        float mu = t1 * (1.f / HW);
        float var = t2 * (1.f / HW) - mu * mu;
        if (var < 0.f) var = 0.f;
        stats[sc * 2]     = mu;
        stats[sc * 2 + 1] = rsqrtf(var + BNEPS);
    }
}

// ---------------------------------------------------------------------------
// Directional gated band scan: each thread owns one (c,h,w), walks 31 bands.
// ---------------------------------------------------------------------------
__global__ __launch_bounds__(256) void band_scan(
        const float* __restrict__ tmp,   // [31,64,HW]
        const float* __restrict__ zpre,  // [31,64,HW]
        const float* __restrict__ stats, // [31*64][2]
        const float* __restrict__ gamma, // [64]
        const float* __restrict__ beta,  // [64]
        float* __restrict__ csc,         // [31,64,HW]
        int fwd)
{
    int idx = blockIdx.x * 256 + threadIdx.x;  // 0 .. 64*HW-1
    int c = idx >> 14;
    float g = gamma[c], be = beta[c];
    float prev = 0.f;
    for (int step = 0; step < S31; step++) {
        int s = fwd ? step : (S31 - 1 - step);
        size_t off = (size_t)s * KC * HW + idx;
        float t  = tmp[off];
        float zp = zpre[off];
        float mu = stats[(s * KC + c) * 2];
        float rs = stats[(s * KC + c) * 2 + 1];
        float zn = (zp - mu) * rs * g + be;
        float z  = 1.f / (1.f + expf(-zn));
        float cur = (step == 0) ? t : (z * prev + (1.f - z) * t);
        csc[off] = cur;
        prev = cur;
    }
}

// ---------------------------------------------------------------------------
extern "C" void kernel_launch(void* const* d_in, const int* in_sizes, int n_in,
                              void* d_out, int out_size, void* d_ws, size_t ws_size,
                              hipStream_t stream) {
    const float* x      = (const float*)d_in[0];   // [1,31,128,128]
    const float* W_fe   = (const float*)d_in[1];
    const float* b_fe   = (const float*)d_in[2];
    const float* W_enc  = (const float*)d_in[3];
    const float* b_enc  = (const float*)d_in[4];
    const float* W_dec  = (const float*)d_in[5];
    const float* b_dec  = (const float*)d_in[6];
    const float* W_last = (const float*)d_in[7];
    const float* b_last = (const float*)d_in[8];
    const float* W_z    = (const float*)d_in[9];
    const float* b_z    = (const float*)d_in[10];
    const float* bn_g   = (const float*)d_in[11];
    const float* bn_b   = (const float*)d_in[12];

    float* out     = (float*)d_out;
    float* csc     = out;                               // [31,1,64,128,128]
    float* outputs = out + (size_t)S31 * KC * HW;       // [1,31,128,128]

    char* ws = (char*)d_ws;
    float* tmp     = (float*)ws; ws += (size_t)S31 * KC * HW * 4;
    float* zpre    = (float*)ws; ws += (size_t)S31 * KC * HW * 4;
    float* res     = (float*)ws; ws += (size_t)S31 * HW * 4;
    float* stats   = (float*)ws; ws += (size_t)S31 * KC * 2 * 4;
    short* wz_frag = (short*)ws; ws += (size_t)3 * KK * 4096 * 2;  // bf16 frags
    float* wenc_r  = (float*)ws; ws += (size_t)3 * KK * KC * 4;
    float* wfe_r   = (float*)ws; ws += (size_t)KK * KC * 4;

    // 1) weight reorder / frag-swizzle
    {
        int total = 3 * KK * 4096 + 3 * KK * KC + KK * KC;  // 614656
        reorder_weights<<<(total + 255) / 256, 256, 0, stream>>>(
            W_z, W_enc, W_fe, wz_frag, wenc_r, wfe_r);
    }

    dim3 gconv(64, S31);

    // 2) csc = softshrink(conv_fe(x))
    conv1to64<<<gconv, 512, 0, stream>>>(x, wfe_r, b_fe, nullptr, csc);

    for (int it = 0; it < 3; it++) {
        int lyr = it;
        // res = x - (conv_dec(csc) + b_dec)
        conv64to1<<<gconv, 256, 0, stream>>>(
            csc, W_dec + (size_t)lyr * KC * KK, b_dec + lyr, x, res);
        // tmp = softshrink(csc + conv_enc(res) + b_enc)
        conv1to64<<<gconv, 512, 0, stream>>>(
            res, wenc_r + (size_t)lyr * KK * KC, b_enc + (size_t)lyr * KC, csc, tmp);
        // zpre = conv_z(tmp) + b_z   (bf16 MFMA shift-GEMM)
        conv_z_mfma<<<gconv, 256, 0, stream>>>(
            tmp, wz_frag + (size_t)lyr * KK * 4096, b_z + (size_t)lyr * KC, zpre);
        // BN stats
        bn_reduce<<<S31 * KC, 256, 0, stream>>>(zpre, stats);
        // gated directional scan -> csc
        band_scan<<<(KC * HW) / 256, 256, 0, stream>>>(
            tmp, zpre, stats, bn_g + (size_t)lyr * KC, bn_b + (size_t)lyr * KC,
            csc, (it % 2 == 0) ? 1 : 0);
    }

    // 3) outputs = conv_last(csc) + b_last
    conv64to1<<<gconv, 256, 0, stream>>>(csc, W_last, b_last, nullptr, outputs);
}